// Round 16
// baseline (86.138 us; speedup 1.0000x reference)
//
#include <hip/hip_runtime.h>
#include <cstdint>

typedef _Float16 f16x8 __attribute__((ext_vector_type(8)));
typedef _Float16 f16x4 __attribute__((ext_vector_type(4)));
typedef float    f32x4 __attribute__((ext_vector_type(4)));

static constexpr int TB = 2;
static constexpr int TT = 2048;
static constexpr int TE = 768;
static constexpr int TH = 12;
static constexpr int TD = 64;
static constexpr int TM = TB * TT;      // 4096 rows (B*T)
static constexpr int TK = TE;           // 768 (K for both GEMMs)
static constexpr int NQKV = 3 * TE;     // 2304

#define SCALE_LOG2E 0.18033688011112042f  /* (1/sqrt(64)) * log2(e) */

// async global->LDS, 16B per lane. LDS dest is wave-uniform base + lane*16.
__device__ __forceinline__ void gload16(const void* g, void* lds) {
  __builtin_amdgcn_global_load_lds(
      (__attribute__((address_space(1))) void*)(uintptr_t)g,
      (__attribute__((address_space(3))) void*)(uint32_t)(uintptr_t)lds, 16, 0, 0);
}

// ---------------------------------------------------------------------------
// f32 -> f16 convert. x -> row-major f16. w_qkv / w_final -> FRAGMENT-NATIVE
// Wf layout: f16 idx(n,k) = ((n>>4)*24 + (k>>5))*512 + ((k>>3)&3)*128
//                           + (n&15)*8 + (k&7)
// ---------------------------------------------------------------------------
__global__ void cvt3(const float* __restrict__ x, const float* __restrict__ wq,
                     const float* __restrict__ wf, _Float16* __restrict__ xh,
                     _Float16* __restrict__ wqh, _Float16* __restrict__ wfh) {
  const int NX = TM * TK / 4, NW = NQKV * TK / 4;
  int i = blockIdx.x * 256 + threadIdx.x;
  if (i < NX) {
    float4 v = ((const float4*)x)[i];
    f16x4 o = {(_Float16)v.x, (_Float16)v.y, (_Float16)v.z, (_Float16)v.w};
    *(f16x4*)&xh[(size_t)i * 4] = o;
  } else {
    const float4* src; _Float16* dst; int j;
    if (i < NX + NW) { src = (const float4*)wq; dst = wqh; j = i - NX; }
    else             { src = (const float4*)wf; dst = wfh; j = i - NX - NW; }
    float4 v = src[j];
    f16x4 o = {(_Float16)v.x, (_Float16)v.y, (_Float16)v.z, (_Float16)v.w};
    const int flat = j * 4;
    const int n = flat / TK, k = flat % TK;
    const size_t idx = ((size_t)(n >> 4) * 24 + (k >> 5)) * 512 +
                       ((k >> 3) & 3) * 128 + (n & 15) * 8 + (k & 7);
    *(f16x4*)&dst[idx] = o;
  }
}

// ---------------------------------------------------------------------------
// NT GEMM (R15, race-fixed triple-buffer): C = A * Wf^T (+bias). 64x128
// tile, BK=64, 4 waves (64x32 out each). ONE barrier/K-step, prefetch
// distance 2: wait vmcnt -> barrier -> issue (ks+2) -> compute(ks).
// EPI=0: qkv epilogue (Q pre-scaled; K',V' fragment-native). EPI=1: f32 out.
// ---------------------------------------------------------------------------
template <int EPI, int MT, int NXT, int MPX>
__global__ __launch_bounds__(MT * 4)
void gemm_nt(const _Float16* __restrict__ A, const _Float16* __restrict__ Bw,
             const float* __restrict__ bias,
             _Float16* __restrict__ qb, _Float16* __restrict__ kb,
             _Float16* __restrict__ vtb, float* __restrict__ outp) {
  __shared__ _Float16 As[3][MT * 64];
  const int tid = threadIdx.x;
  const int w = tid >> 6, lane = tid & 63;
  const int lr = lane & 15, lk = lane >> 4;

  const int id = blockIdx.x;
  const int xcd = id & 7, j = id >> 3;
  const int m0 = (xcd * MPX + j / NXT) * MT;
  const int n0 = (j % NXT) * 128;
  const int wr = (MT == 128) ? (w >> 2) : 0;
  const int wc = (MT == 128) ? (w & 3) : w;

  f32x4 acc[4][2] = {};
  const char* Ab = (const char*)(A + (size_t)m0 * TK);
  const char* WB = (const char*)Bw;
  const int nb = (n0 >> 4) + wc * 2;
  constexpr int NS = TK / 64;  // 12 K-steps

  auto loadB = [&](int ks, f16x8 (&bf)[2][2]) {
#pragma unroll
    for (int ni = 0; ni < 2; ++ni)
#pragma unroll
      for (int kc = 0; kc < 2; ++kc)
        bf[ni][kc] = *(const f16x8*)(WB +
                                     ((size_t)(nb + ni) * 24 + ks * 2 + kc) * 1024 +
                                     lane * 16);
  };
  auto stageA = [&](int ks, _Float16* L) {
#pragma unroll
    for (int c = 0; c < 2; ++c) {
      int g = w * 2 + c;  // chunk of the MT*128B A tile
      int o = g * 1024 + lane * 16;
      int row = o >> 7, ch = (o >> 4) & 7;
      gload16(Ab + (size_t)row * (TK * 2) + ks * 128 + ((ch ^ (row & 7)) << 4),
              (char*)L + g * 1024);
    }
  };
  auto step = [&](f16x8 (&bc)[2][2], f16x8 (&bn)[2][2], _Float16* Lc,
                  _Float16* Ln, int ks) {
    if (ks < NS - 1) {
      asm volatile("s_waitcnt vmcnt(6)" ::: "memory");  // step ks's 6 landed
    } else {
      asm volatile("s_waitcnt vmcnt(0)" ::: "memory");
    }
    __builtin_amdgcn_s_barrier();  // publish ks; fence off compute(ks-1)
    if (ks < NS - 2) {
      loadB(ks + 2, bn);   // 4 reg loads (consumed at step ks+2)
      stageA(ks + 2, Ln);  // 2 gload16 -> As[(ks+2)%3] (WAR-safe)
    }
#pragma unroll
    for (int kc = 0; kc < 2; ++kc) {
      f16x8 af[4];
#pragma unroll
      for (int mi = 0; mi < 4; ++mi) {
        int row = wr * 64 + mi * 16 + lr;
        af[mi] = *(const f16x8*)&Lc[row * 64 + (((kc * 4 + lk) ^ (row & 7)) << 3)];
      }
#pragma unroll
      for (int mi = 0; mi < 4; ++mi)
#pragma unroll
        for (int ni = 0; ni < 2; ++ni)
          acc[mi][ni] = __builtin_amdgcn_mfma_f32_16x16x32_f16(af[mi], bc[ni][kc],
                                                               acc[mi][ni], 0, 0, 0);
    }
  };

  f16x8 b0[2][2], b1[2][2], b2[2][2];
  loadB(0, b0);
  stageA(0, As[0]);
  loadB(1, b1);
  stageA(1, As[1]);
  for (int kss = 0; kss < NS; kss += 3) {  // NS=12: buffer indices fold
    step(b0, b2, As[0], As[2], kss);
    step(b1, b0, As[1], As[0], kss + 1);
    step(b2, b1, As[2], As[1], kss + 2);
  }

  // epilogue: C layout col = lane&15 (N), row = (lane>>4)*4 + r
#pragma unroll
  for (int mi = 0; mi < 4; ++mi) {
#pragma unroll
    for (int ni = 0; ni < 2; ++ni) {
      const int col = n0 + wc * 32 + ni * 16 + lr;
#pragma unroll
      for (int r = 0; r < 4; ++r) {
        const int row = m0 + wr * 64 + mi * 16 + lk * 4 + r;
        float v = acc[mi][ni][r];
        if (EPI == 0) {
          v += bias[col];
          const int which = (col >= 2 * TE) ? 2 : (col >= TE ? 1 : 0);
          const int e = col - which * TE;
          const int h = e >> 6, d = e & 63;
          const int b = row >> 11, t = row & (TT - 1);
          const size_t hb = (size_t)(b * TH + h);
          if (which == 0) {
            qb[(hb * TT + t) * TD + d] = (_Float16)(v * SCALE_LOG2E);
          } else if (which == 1) {
            // K' fragment-native
            kb[((((hb * 128 + (t >> 4)) * 8 + (d >> 3)) * 16 + (t & 15)) * 8) +
               (d & 7)] = (_Float16)v;
          } else {
            // V' fragment-native
            const int kc = (t >> 5) & 1, hi = (t >> 4) & 1;
            const int lkv = (t >> 2) & 3, m = t & 3;
            vtb[((((((hb * 32 + (t >> 6)) * 4 + (d >> 4)) * 2 + kc) * 4 + lkv) *
                      16 +
                  (d & 15)) *
                 8) +
                (hi * 4 + m)] = (_Float16)v;
          }
        } else {
          outp[(size_t)row * TE + col] = v;
        }
      }
    }
  }
}

// ---------------------------------------------------------------------------
// Causal flash attention, reg-direct (R7 pipeline), UNIFORM-RUNTIME blocks:
// qt >= 16 units are split into TWO blocks over the s-range (each <= 16
// phases, partials merged by merge_kernel); qt < 16 units are one block.
// Grid 1152 = 24 heads x 48 slots (heavy halves first; head = id%24 keeps
// each head on one XCD since 24 % 8 == 0). ~4.5 blocks/CU, all co-resident
// -> no 32-phase serial tail (the R15 binder). 4 independent waves/block;
// wave w owns 16 q-rows. K,V fragment-native -> contiguous 1KB wave loads
// to VGPR; kfA/kfB reg dbuf (K prefetched 2 tiles ahead), V at phase start.
// SWAPPED QK^T: lane-local softmax; P in registers. T13 defer-max (thr=8).
// Heavy halves store (m f32, l f32, O/l f16) to scratch; O/l bounded by
// max|V| so f16-safe regardless of defer-max magnitudes.
// ---------------------------------------------------------------------------
__global__ __launch_bounds__(256)
void attn_kernel(const _Float16* __restrict__ qbuf, const _Float16* __restrict__ kbuf,
                 const _Float16* __restrict__ vtbuf, _Float16* __restrict__ ob,
                 float* __restrict__ pm, float* __restrict__ pl,
                 _Float16* __restrict__ po) {
  const int tid = threadIdx.x, w = tid >> 6, lane = tid & 63;
  const int lr = lane & 15, lk = lane >> 4;

  const int id = blockIdx.x;       // 0..1151
  const int bh = id % 24;
  const int slot = id / 24;        // 0..47, heavy halves first
  int qt, sBeg, sEnd, part, heavy;
  if (slot < 32) {
    heavy = 1;
    qt = 31 - (slot >> 1);
    part = slot & 1;
    const int half = (qt + 2) >> 1;  // ceil((qt+1)/2)
    sBeg = part ? half : 0;
    sEnd = part ? qt + 1 : half;
  } else {
    heavy = 0;
    qt = 47 - slot;                // 15..0
    part = 0;
    sBeg = 0;
    sEnd = qt + 1;
  }
  const int t0 = qt * 64;
  const int last = sEnd - 1;

  const _Float16* q = qbuf + (size_t)bh * (TT * TD);  // [T][64], pre-scaled
  const char* kbase =
      (const char*)(kbuf + (size_t)bh * (TT * TD)) + lk * 256 + lr * 16;
  const char* vbase =
      (const char*)(vtbuf + (size_t)bh * (TT * TD)) + lk * 256 + lr * 16;

  f16x8 qf[2];  // B-operand: Q[q=t0+w*16+lr][kc*32+lk*8 ..]
#pragma unroll
  for (int kc = 0; kc < 2; ++kc)
    qf[kc] = *(const f16x8*)&q[(size_t)(t0 + w * 16 + lr) * TD + kc * 32 + lk * 8];

  f32x4 of[4] = {};                 // O[q=lk*4+r][d=nd*16+lr]
  float mrun = -1e30f, lrun = 0.f;  // softmax state for q = lane&15 (x4 replicas)

  f16x8 kfA[2][4], kfB[2][4], vf[2][4];

  // prologue: K(sBeg) -> kfA, K(sBeg+1 clamped) -> kfB
  {
    const char* k0 = kbase + (size_t)sBeg * 8192;
    const char* k1 = kbase + (size_t)((sBeg + 1 <= last) ? sBeg + 1 : last) * 8192;
#pragma unroll
    for (int kc = 0; kc < 2; ++kc)
#pragma unroll
      for (int ni = 0; ni < 4; ++ni) {
        kfA[kc][ni] = *(const f16x8*)(k0 + ni * 2048 + kc * 1024);
        kfB[kc][ni] = *(const f16x8*)(k1 + ni * 2048 + kc * 1024);
      }
  }

  auto phase = [&](f16x8 (&kf)[2][4], int st) {
    // issue V(st) loads (consumed by PV below; cover = QK^T + softmax)
    const char* vt = vbase + (size_t)st * 8192;
#pragma unroll
    for (int kc = 0; kc < 2; ++kc)
#pragma unroll
      for (int nd = 0; nd < 4; ++nd)
        vf[kc][nd] = *(const f16x8*)(vt + nd * 2048 + kc * 1024);

    // S^T: sa[ni] = mfma(K, Q): lane holds S[s=st*64+ni*16+lk*4+r][q=lr]
    f32x4 sa[4] = {};
    __builtin_amdgcn_s_setprio(1);
#pragma unroll
    for (int kc = 0; kc < 2; ++kc)
#pragma unroll
      for (int ni = 0; ni < 4; ++ni)
        sa[ni] =
            __builtin_amdgcn_mfma_f32_16x16x32_f16(kf[kc][ni], qf[kc], sa[ni], 0, 0, 0);
    __builtin_amdgcn_s_setprio(0);

    // prefetch K(st+2) into the buffer just consumed (clamped to last)
    {
      const int stp = (st + 2 <= last) ? st + 2 : last;
      const char* kt = kbase + (size_t)stp * 8192;
#pragma unroll
      for (int kc = 0; kc < 2; ++kc)
#pragma unroll
        for (int ni = 0; ni < 4; ++ni)
          kf[kc][ni] = *(const f16x8*)(kt + ni * 2048 + kc * 1024);
    }

    if (st == qt) {  // diagonal tile: causal mask (s > q)
      const int s0 = st * 64;
#pragma unroll
      for (int ni = 0; ni < 4; ++ni)
#pragma unroll
        for (int r = 0; r < 4; ++r)
          if (s0 + ni * 16 + lk * 4 + r > t0 + w * 16 + lr) sa[ni][r] = -1e30f;
    }

    // lane-local row max, then reduce over the 4 replica lanes
    float mx;
    {
      float m0_ = fmaxf(fmaxf(sa[0][0], sa[0][1]), fmaxf(sa[0][2], sa[0][3]));
      float m1_ = fmaxf(fmaxf(sa[1][0], sa[1][1]), fmaxf(sa[1][2], sa[1][3]));
      float m2_ = fmaxf(fmaxf(sa[2][0], sa[2][1]), fmaxf(sa[2][2], sa[2][3]));
      float m3_ = fmaxf(fmaxf(sa[3][0], sa[3][1]), fmaxf(sa[3][2], sa[3][3]));
      mx = fmaxf(fmaxf(m0_, m1_), fmaxf(m2_, m3_));
      mx = fmaxf(mx, __shfl_xor(mx, 16));
      mx = fmaxf(mx, __shfl_xor(mx, 32));
    }

    // defer-max: rescale only when the wave sees max growth > 8 (log2 units)
    if (__any(mx > mrun + 8.0f)) {
      float mn = fmaxf(mrun, mx);
      float al = __builtin_amdgcn_exp2f(mrun - mn);
      mrun = mn;
      lrun *= al;
      float al4[4];
#pragma unroll
      for (int r = 0; r < 4; ++r) al4[r] = __shfl(al, lk * 4 + r);
#pragma unroll
      for (int nd = 0; nd < 4; ++nd)
#pragma unroll
        for (int r = 0; r < 4; ++r) of[nd][r] *= al4[r];
    }

    // P = exp2(sa - mrun); pack PV A-fragments: pa[kc] slot 4*hi+m holds
    // P[q=lr][s = 32kc + 16hi + 4lk + m]  (hi = ni&1, m = r)
    f16x8 pa[2];
    float rs;
    {
      float rn[4];
#pragma unroll
      for (int ni = 0; ni < 4; ++ni) {
        float p0 = __builtin_amdgcn_exp2f(sa[ni][0] - mrun);
        float p1 = __builtin_amdgcn_exp2f(sa[ni][1] - mrun);
        float p2 = __builtin_amdgcn_exp2f(sa[ni][2] - mrun);
        float p3 = __builtin_amdgcn_exp2f(sa[ni][3] - mrun);
        rn[ni] = (p0 + p1) + (p2 + p3);
        pa[ni >> 1][(ni & 1) * 4 + 0] = (_Float16)p0;
        pa[ni >> 1][(ni & 1) * 4 + 1] = (_Float16)p1;
        pa[ni >> 1][(ni & 1) * 4 + 2] = (_Float16)p2;
        pa[ni >> 1][(ni & 1) * 4 + 3] = (_Float16)p3;
      }
      rs = (rn[0] + rn[1]) + (rn[2] + rn[3]);
      rs += __shfl_xor(rs, 16);
      rs += __shfl_xor(rs, 32);
    }
    lrun += rs;

    // O += P V (B-fragment = vf, slot j = hi*4+m matches pa by construction)
    __builtin_amdgcn_s_setprio(1);
#pragma unroll
    for (int kc = 0; kc < 2; ++kc)
#pragma unroll
      for (int nd = 0; nd < 4; ++nd)
        of[nd] =
            __builtin_amdgcn_mfma_f32_16x16x32_f16(pa[kc], vf[kc][nd], of[nd], 0, 0, 0);
    __builtin_amdgcn_s_setprio(0);
  };

  int st = sBeg;
  while (st + 1 < sEnd) {
    phase(kfA, st);
    phase(kfB, st + 1);
    st += 2;
  }
  if (st < sEnd) phase(kfA, st);

  // per-row l for rows lk*4+r (owner lane lr = row-in-16)
  float linv[4];
#pragma unroll
  for (int r = 0; r < 4; ++r) linv[r] = __shfl(lrun, lk * 4 + r);

  if (!heavy) {
    const int b = bh / TH, h = bh - b * TH;
#pragma unroll
    for (int nd = 0; nd < 4; ++nd)
#pragma unroll
      for (int r = 0; r < 4; ++r) {
        int tg = t0 + w * 16 + lk * 4 + r;
        int d = nd * 16 + lr;
        ob[(size_t)(b * TT + tg) * TE + h * TD + d] =
            (_Float16)(of[nd][r] / linv[r]);
      }
  } else {
    // scratch unit u; store m,l (rows w*16+lr from lanes lk==0) and O/l f16
    const int u = (bh * 16 + (qt - 16)) * 2 + part;
    if (lk == 0) {
      pm[u * 64 + w * 16 + lr] = mrun;
      pl[u * 64 + w * 16 + lr] = lrun;
    }
#pragma unroll
    for (int nd = 0; nd < 4; ++nd)
#pragma unroll
      for (int r = 0; r < 4; ++r) {
        int row = w * 16 + lk * 4 + r;
        int d = nd * 16 + lr;
        po[(size_t)u * 4096 + row * 64 + d] = (_Float16)(of[nd][r] / linv[r]);
      }
  }
}

// ---------------------------------------------------------------------------
// Merge the two s-halves of each heavy unit: out = (w0*O0^ + w1*O1^) with
// w_i = exp2(m_i - mmax) * l_i, normalized. 384 blocks (bh, qidx); 256 thr:
// thread handles one row x 16 d's.
// ---------------------------------------------------------------------------
__global__ __launch_bounds__(256)
void merge_kernel(const float* __restrict__ pm, const float* __restrict__ pl,
                  const _Float16* __restrict__ po, _Float16* __restrict__ ob) {
  const int bh = blockIdx.x % 24, qidx = blockIdx.x / 24;  // qidx 0..15
  const int qt = 16 + qidx;
  const int u0 = (bh * 16 + qidx) * 2, u1 = u0 + 1;
  const int row = threadIdx.x >> 2;
  const int d0 = (threadIdx.x & 3) * 16;

  const float m0 = pm[u0 * 64 + row], m1 = pm[u1 * 64 + row];
  const float l0 = pl[u0 * 64 + row], l1 = pl[u1 * 64 + row];
  const float mm = fmaxf(m0, m1);
  float w0 = __builtin_amdgcn_exp2f(m0 - mm) * l0;
  float w1 = __builtin_amdgcn_exp2f(m1 - mm) * l1;
  const float rden = 1.0f / (w0 + w1);
  w0 *= rden;
  w1 *= rden;

  const int b = bh / TH, h = bh - b * TH;
  const int tg = qt * 64 + row;
  const _Float16* o0 = po + (size_t)u0 * 4096 + row * 64 + d0;
  const _Float16* o1 = po + (size_t)u1 * 4096 + row * 64 + d0;
  _Float16* dst = ob + (size_t)(b * TT + tg) * TE + h * TD + d0;
#pragma unroll
  for (int j = 0; j < 16; ++j)
    dst[j] = (_Float16)(w0 * (float)o0[j] + w1 * (float)o1[j]);
}

// ---------------------------------------------------------------------------
extern "C" void kernel_launch(void* const* d_in, const int* in_sizes, int n_in,
                              void* d_out, int out_size, void* d_ws, size_t ws_size,
                              hipStream_t stream) {
  const float* x    = (const float*)d_in[0];
  const float* wqkv = (const float*)d_in[1];
  const float* bqkv = (const float*)d_in[2];
  const float* wfin = (const float*)d_in[3];
  float* out = (float*)d_out;

  _Float16* xh  = (_Float16*)d_ws;          // [4096][768] row-major
  _Float16* wqh = xh + (size_t)TM * TK;     // fragment-native Wf
  _Float16* wfh = wqh + (size_t)NQKV * TK;  // fragment-native Wf
  _Float16* qb  = wfh + (size_t)TE * TE;    // [B,H,T,D] (pre-scaled)
  _Float16* kb  = qb + (size_t)TM * TE;     // K' fragment-native
  _Float16* vtb = kb + (size_t)TM * TE;     // V' fragment-native
  _Float16* ob  = vtb + (size_t)TM * TE;    // [4096][768] attn output
  _Float16* po  = ob + (size_t)TM * TE;     // heavy-half O/l partials (6.3MB)
  float* pm = (float*)(po + (size_t)768 * 4096);  // 768 units x 64 rows
  float* pl = pm + 768 * 64;

  cvt3<<<5376, 256, 0, stream>>>(x, wqkv, wfin, xh, wqh, wfh);
  gemm_nt<0, 64, NQKV / 128, 8><<<8 * 8 * (NQKV / 128), 256, 0, stream>>>(
      xh, wqh, bqkv, qb, kb, vtb, nullptr);
  attn_kernel<<<24 * 48, 256, 0, stream>>>(qb, kb, vtb, ob, pm, pl, po);
  merge_kernel<<<24 * 16, 256, 0, stream>>>(pm, pl, po, ob);
  gemm_nt<1, 64, TE / 128, 8><<<8 * 8 * (TE / 128), 256, 0, stream>>>(
      ob, wfh, nullptr, nullptr, nullptr, nullptr, out);
}

// Round 17
// 85.744 us; speedup vs baseline: 1.0046x; 1.0046x over previous
//
#include <hip/hip_runtime.h>
#include <cstdint>

typedef _Float16 f16x8 __attribute__((ext_vector_type(8)));
typedef _Float16 f16x4 __attribute__((ext_vector_type(4)));
typedef float    f32x4 __attribute__((ext_vector_type(4)));

static constexpr int TB = 2;
static constexpr int TT = 2048;
static constexpr int TE = 768;
static constexpr int TH = 12;
static constexpr int TD = 64;
static constexpr int TM = TB * TT;      // 4096 rows (B*T)
static constexpr int TK = TE;           // 768 (K for both GEMMs)
static constexpr int NQKV = 3 * TE;     // 2304

#define SCALE_LOG2E 0.18033688011112042f  /* (1/sqrt(64)) * log2(e) */

// async global->LDS, 16B per lane. LDS dest is wave-uniform base + lane*16.
__device__ __forceinline__ void gload16(const void* g, void* lds) {
  __builtin_amdgcn_global_load_lds(
      (__attribute__((address_space(1))) void*)(uintptr_t)g,
      (__attribute__((address_space(3))) void*)(uint32_t)(uintptr_t)lds, 16, 0, 0);
}

// ---------------------------------------------------------------------------
// f32 -> f16 convert. x -> row-major f16. w_qkv / w_final -> FRAGMENT-NATIVE
// Wf layout: f16 idx(n,k) = ((n>>4)*24 + (k>>5))*512 + ((k>>3)&3)*128
//                           + (n&15)*8 + (k&7)
// ---------------------------------------------------------------------------
__global__ void cvt3(const float* __restrict__ x, const float* __restrict__ wq,
                     const float* __restrict__ wf, _Float16* __restrict__ xh,
                     _Float16* __restrict__ wqh, _Float16* __restrict__ wfh) {
  const int NX = TM * TK / 4, NW = NQKV * TK / 4;
  int i = blockIdx.x * 256 + threadIdx.x;
  if (i < NX) {
    float4 v = ((const float4*)x)[i];
    f16x4 o = {(_Float16)v.x, (_Float16)v.y, (_Float16)v.z, (_Float16)v.w};
    *(f16x4*)&xh[(size_t)i * 4] = o;
  } else {
    const float4* src; _Float16* dst; int j;
    if (i < NX + NW) { src = (const float4*)wq; dst = wqh; j = i - NX; }
    else             { src = (const float4*)wf; dst = wfh; j = i - NX - NW; }
    float4 v = src[j];
    f16x4 o = {(_Float16)v.x, (_Float16)v.y, (_Float16)v.z, (_Float16)v.w};
    const int flat = j * 4;
    const int n = flat / TK, k = flat % TK;
    const size_t idx = ((size_t)(n >> 4) * 24 + (k >> 5)) * 512 +
                       ((k >> 3) & 3) * 128 + (n & 15) * 8 + (k & 7);
    *(f16x4*)&dst[idx] = o;
  }
}

// ---------------------------------------------------------------------------
// NT GEMM (R15, race-fixed triple-buffer): C = A * Wf^T (+bias). 64x128
// tile, BK=64, 4 waves (64x32 out each). ONE barrier/K-step, prefetch
// distance 2: wait vmcnt -> barrier -> issue (ks+2) -> compute(ks).
// EPI=0: qkv epilogue (Q pre-scaled; K',V' fragment-native). EPI=1: f32 out.
// ---------------------------------------------------------------------------
template <int EPI, int MT, int NXT, int MPX>
__global__ __launch_bounds__(MT * 4)
void gemm_nt(const _Float16* __restrict__ A, const _Float16* __restrict__ Bw,
             const float* __restrict__ bias,
             _Float16* __restrict__ qb, _Float16* __restrict__ kb,
             _Float16* __restrict__ vtb, float* __restrict__ outp) {
  __shared__ _Float16 As[3][MT * 64];
  const int tid = threadIdx.x;
  const int w = tid >> 6, lane = tid & 63;
  const int lr = lane & 15, lk = lane >> 4;

  const int id = blockIdx.x;
  const int xcd = id & 7, j = id >> 3;
  const int m0 = (xcd * MPX + j / NXT) * MT;
  const int n0 = (j % NXT) * 128;
  const int wr = (MT == 128) ? (w >> 2) : 0;
  const int wc = (MT == 128) ? (w & 3) : w;

  f32x4 acc[4][2] = {};
  const char* Ab = (const char*)(A + (size_t)m0 * TK);
  const char* WB = (const char*)Bw;
  const int nb = (n0 >> 4) + wc * 2;
  constexpr int NS = TK / 64;  // 12 K-steps

  auto loadB = [&](int ks, f16x8 (&bf)[2][2]) {
#pragma unroll
    for (int ni = 0; ni < 2; ++ni)
#pragma unroll
      for (int kc = 0; kc < 2; ++kc)
        bf[ni][kc] = *(const f16x8*)(WB +
                                     ((size_t)(nb + ni) * 24 + ks * 2 + kc) * 1024 +
                                     lane * 16);
  };
  auto stageA = [&](int ks, _Float16* L) {
#pragma unroll
    for (int c = 0; c < 2; ++c) {
      int g = w * 2 + c;  // chunk of the MT*128B A tile
      int o = g * 1024 + lane * 16;
      int row = o >> 7, ch = (o >> 4) & 7;
      gload16(Ab + (size_t)row * (TK * 2) + ks * 128 + ((ch ^ (row & 7)) << 4),
              (char*)L + g * 1024);
    }
  };
  auto step = [&](f16x8 (&bc)[2][2], f16x8 (&bn)[2][2], _Float16* Lc,
                  _Float16* Ln, int ks) {
    if (ks < NS - 1) {
      asm volatile("s_waitcnt vmcnt(6)" ::: "memory");  // step ks's 6 landed
    } else {
      asm volatile("s_waitcnt vmcnt(0)" ::: "memory");
    }
    __builtin_amdgcn_s_barrier();  // publish ks; fence off compute(ks-1)
    if (ks < NS - 2) {
      loadB(ks + 2, bn);   // 4 reg loads (consumed at step ks+2)
      stageA(ks + 2, Ln);  // 2 gload16 -> As[(ks+2)%3] (WAR-safe)
    }
#pragma unroll
    for (int kc = 0; kc < 2; ++kc) {
      f16x8 af[4];
#pragma unroll
      for (int mi = 0; mi < 4; ++mi) {
        int row = wr * 64 + mi * 16 + lr;
        af[mi] = *(const f16x8*)&Lc[row * 64 + (((kc * 4 + lk) ^ (row & 7)) << 3)];
      }
#pragma unroll
      for (int mi = 0; mi < 4; ++mi)
#pragma unroll
        for (int ni = 0; ni < 2; ++ni)
          acc[mi][ni] = __builtin_amdgcn_mfma_f32_16x16x32_f16(af[mi], bc[ni][kc],
                                                               acc[mi][ni], 0, 0, 0);
    }
  };

  f16x8 b0[2][2], b1[2][2], b2[2][2];
  loadB(0, b0);
  stageA(0, As[0]);
  loadB(1, b1);
  stageA(1, As[1]);
  for (int kss = 0; kss < NS; kss += 3) {  // NS=12: buffer indices fold
    step(b0, b2, As[0], As[2], kss);
    step(b1, b0, As[1], As[0], kss + 1);
    step(b2, b1, As[2], As[1], kss + 2);
  }

  // epilogue: C layout col = lane&15 (N), row = (lane>>4)*4 + r
#pragma unroll
  for (int mi = 0; mi < 4; ++mi) {
#pragma unroll
    for (int ni = 0; ni < 2; ++ni) {
      const int col = n0 + wc * 32 + ni * 16 + lr;
#pragma unroll
      for (int r = 0; r < 4; ++r) {
        const int row = m0 + wr * 64 + mi * 16 + lk * 4 + r;
        float v = acc[mi][ni][r];
        if (EPI == 0) {
          v += bias[col];
          const int which = (col >= 2 * TE) ? 2 : (col >= TE ? 1 : 0);
          const int e = col - which * TE;
          const int h = e >> 6, d = e & 63;
          const int b = row >> 11, t = row & (TT - 1);
          const size_t hb = (size_t)(b * TH + h);
          if (which == 0) {
            qb[(hb * TT + t) * TD + d] = (_Float16)(v * SCALE_LOG2E);
          } else if (which == 1) {
            // K' fragment-native
            kb[((((hb * 128 + (t >> 4)) * 8 + (d >> 3)) * 16 + (t & 15)) * 8) +
               (d & 7)] = (_Float16)v;
          } else {
            // V' fragment-native
            const int kc = (t >> 5) & 1, hi = (t >> 4) & 1;
            const int lkv = (t >> 2) & 3, m = t & 3;
            vtb[((((((hb * 32 + (t >> 6)) * 4 + (d >> 4)) * 2 + kc) * 4 + lkv) *
                      16 +
                  (d & 15)) *
                 8) +
                (hi * 4 + m)] = (_Float16)v;
          }
        } else {
          outp[(size_t)row * TE + col] = v;
        }
      }
    }
  }
}

// ---------------------------------------------------------------------------
// Causal flash attention, LDS-STAGED KV, triple-buffered (R15 GEMM schedule
// ported). Grid 768 = 24 heads x 32 q-tiles (bh = id%24, qt = 31 - id/24).
// 4 waves/block; wave w owns 16 q-rows. Per phase the block stages ONE
// 16KB K+V tile into LDS (16 gload16, 4/wave) -> eliminates the 4x
// per-wave redundant L1 loads that bound R7-R16 (811 MB -> 203 MB).
// Schedule per phase: wait counted vmcnt (certify phase st's chunks) ->
// ONE s_barrier (publish; fences compute(st-1)) -> stage KV(st+2) into
// buffer (st+2)%3 (WAR-safe: its readers, compute(st-1), all finished
// before this barrier) -> compute(st) from buffer st%3.
// vmcnt: 4 gload16/wave/stage; steady outstanding 8 -> vmcnt(4); last
// phase vmcnt(0). Fragment reads: uniform base + lane*16 ds_read_b128,
// conflict-free (R5-measured 0 conflicts). SWAPPED QK^T: lane-local
// softmax; P in registers. T13 defer-max (thr=8, log2 domain).
// ---------------------------------------------------------------------------
__global__ __launch_bounds__(256)
void attn_kernel(const _Float16* __restrict__ qbuf, const _Float16* __restrict__ kbuf,
                 const _Float16* __restrict__ vtbuf, _Float16* __restrict__ ob) {
  __shared__ _Float16 KV[3][8192];  // 3 x (K 8KB + V 8KB) = 48KB
  const int tid = threadIdx.x, w = tid >> 6, lane = tid & 63;
  const int lr = lane & 15, lk = lane >> 4;

  const int id = blockIdx.x;        // 0..767
  const int bh = id % 24;
  const int qt = 31 - id / 24;      // heavy first, balanced per CU
  const int t0 = qt * 64;
  const int nt = qt + 1;

  const _Float16* q = qbuf + (size_t)bh * (TT * TD);  // [T][64], pre-scaled
  const char* kg = (const char*)(kbuf + (size_t)bh * (TT * TD));
  const char* vg = (const char*)(vtbuf + (size_t)bh * (TT * TD));

  // stage tile st into LDS buffer buf: 16 chunks of 1KB; wave w does 4.
  // chunks 0-7 = K fragments, 8-15 = V fragments (linear copy).
  auto stage = [&](int st, int buf) {
    char* Lb = (char*)KV[buf];
    const char* base = (w < 2) ? kg : vg;  // wave-uniform
#pragma unroll
    for (int c4 = 0; c4 < 4; ++c4) {
      const int cl = (w & 1) * 4 + c4;  // 0..7 within K or V
      gload16(base + (size_t)st * 8192 + cl * 1024 + lane * 16,
              Lb + ((w < 2) ? 0 : 8192) + cl * 1024);
    }
  };

  f16x8 qf[2];  // B-operand: Q[q=t0+w*16+lr][kc*32+lk*8 ..]
#pragma unroll
  for (int kc = 0; kc < 2; ++kc)
    qf[kc] = *(const f16x8*)&q[(size_t)(t0 + w * 16 + lr) * TD + kc * 32 + lk * 8];

  f32x4 of[4] = {};                 // O[q=lk*4+r][d=nd*16+lr]
  float mrun = -1e30f, lrun = 0.f;  // softmax state for q = lane&15 (x4 replicas)

  // prologue: KV(0) -> buf0, KV(1 clamped) -> buf1
  stage(0, 0);
  stage((nt > 1) ? 1 : 0, 1);

  int cur = 0;
  for (int st = 0; st < nt; ++st) {
    if (st < nt - 1) {
      asm volatile("s_waitcnt vmcnt(4)" ::: "memory");  // phase st's 4 landed
    } else {
      asm volatile("s_waitcnt vmcnt(0)" ::: "memory");
    }
    __builtin_amdgcn_s_barrier();  // publish st; fence off compute(st-1)
    if (st + 2 < nt) {
      int b2 = cur + 2;
      if (b2 >= 3) b2 -= 3;
      stage(st + 2, b2);  // WAR-safe (readers finished before barrier)
    }

    const char* Lb = (const char*)KV[cur];
    // fragment loads from LDS: uniform base + lane*16 (conflict-free)
    f16x8 kf[2][4], vf[2][4];
#pragma unroll
    for (int kc = 0; kc < 2; ++kc)
#pragma unroll
      for (int ni = 0; ni < 4; ++ni)
        kf[kc][ni] = *(const f16x8*)(Lb + ni * 2048 + kc * 1024 + lane * 16);
#pragma unroll
    for (int kc = 0; kc < 2; ++kc)
#pragma unroll
      for (int nd = 0; nd < 4; ++nd)
        vf[kc][nd] =
            *(const f16x8*)(Lb + 8192 + nd * 2048 + kc * 1024 + lane * 16);

    // S^T: sa[ni] = mfma(K, Q): lane holds S[s=st*64+ni*16+lk*4+r][q=lr]
    f32x4 sa[4] = {};
    __builtin_amdgcn_s_setprio(1);
#pragma unroll
    for (int kc = 0; kc < 2; ++kc)
#pragma unroll
      for (int ni = 0; ni < 4; ++ni)
        sa[ni] =
            __builtin_amdgcn_mfma_f32_16x16x32_f16(kf[kc][ni], qf[kc], sa[ni], 0, 0, 0);
    __builtin_amdgcn_s_setprio(0);

    if (st == nt - 1) {  // diagonal tile: causal mask (s > q)
      const int s0 = st * 64;
#pragma unroll
      for (int ni = 0; ni < 4; ++ni)
#pragma unroll
        for (int r = 0; r < 4; ++r)
          if (s0 + ni * 16 + lk * 4 + r > t0 + w * 16 + lr) sa[ni][r] = -1e30f;
    }

    // lane-local row max, then reduce over the 4 replica lanes
    float mx;
    {
      float m0_ = fmaxf(fmaxf(sa[0][0], sa[0][1]), fmaxf(sa[0][2], sa[0][3]));
      float m1_ = fmaxf(fmaxf(sa[1][0], sa[1][1]), fmaxf(sa[1][2], sa[1][3]));
      float m2_ = fmaxf(fmaxf(sa[2][0], sa[2][1]), fmaxf(sa[2][2], sa[2][3]));
      float m3_ = fmaxf(fmaxf(sa[3][0], sa[3][1]), fmaxf(sa[3][2], sa[3][3]));
      mx = fmaxf(fmaxf(m0_, m1_), fmaxf(m2_, m3_));
      mx = fmaxf(mx, __shfl_xor(mx, 16));
      mx = fmaxf(mx, __shfl_xor(mx, 32));
    }

    // defer-max: rescale only when the wave sees max growth > 8 (log2 units)
    if (__any(mx > mrun + 8.0f)) {
      float mn = fmaxf(mrun, mx);
      float al = __builtin_amdgcn_exp2f(mrun - mn);
      mrun = mn;
      lrun *= al;
      float al4[4];
#pragma unroll
      for (int r = 0; r < 4; ++r) al4[r] = __shfl(al, lk * 4 + r);
#pragma unroll
      for (int nd = 0; nd < 4; ++nd)
#pragma unroll
        for (int r = 0; r < 4; ++r) of[nd][r] *= al4[r];
    }

    // P = exp2(sa - mrun); pack PV A-fragments: pa[kc] slot 4*hi+m holds
    // P[q=lr][s = 32kc + 16hi + 4lk + m]  (hi = ni&1, m = r)
    f16x8 pa[2];
    float rs;
    {
      float rn[4];
#pragma unroll
      for (int ni = 0; ni < 4; ++ni) {
        float p0 = __builtin_amdgcn_exp2f(sa[ni][0] - mrun);
        float p1 = __builtin_amdgcn_exp2f(sa[ni][1] - mrun);
        float p2 = __builtin_amdgcn_exp2f(sa[ni][2] - mrun);
        float p3 = __builtin_amdgcn_exp2f(sa[ni][3] - mrun);
        rn[ni] = (p0 + p1) + (p2 + p3);
        pa[ni >> 1][(ni & 1) * 4 + 0] = (_Float16)p0;
        pa[ni >> 1][(ni & 1) * 4 + 1] = (_Float16)p1;
        pa[ni >> 1][(ni & 1) * 4 + 2] = (_Float16)p2;
        pa[ni >> 1][(ni & 1) * 4 + 3] = (_Float16)p3;
      }
      rs = (rn[0] + rn[1]) + (rn[2] + rn[3]);
      rs += __shfl_xor(rs, 16);
      rs += __shfl_xor(rs, 32);
    }
    lrun += rs;

    // O += P V (B-fragment = vf, slot j = hi*4+m matches pa by construction)
    __builtin_amdgcn_s_setprio(1);
#pragma unroll
    for (int kc = 0; kc < 2; ++kc)
#pragma unroll
      for (int nd = 0; nd < 4; ++nd)
        of[nd] =
            __builtin_amdgcn_mfma_f32_16x16x32_f16(pa[kc], vf[kc][nd], of[nd], 0, 0, 0);
    __builtin_amdgcn_s_setprio(0);

    cur = (cur + 1 == 3) ? 0 : cur + 1;
  }

  // epilogue: need lrun for q = lk*4+r (owner lane lr = q)
  float linv[4];
#pragma unroll
  for (int r = 0; r < 4; ++r) linv[r] = __shfl(lrun, lk * 4 + r);
  const int b = bh / TH, h = bh - b * TH;
#pragma unroll
  for (int nd = 0; nd < 4; ++nd) {
#pragma unroll
    for (int r = 0; r < 4; ++r) {
      int tg = t0 + w * 16 + lk * 4 + r;
      int d = nd * 16 + lr;
      ob[(size_t)(b * TT + tg) * TE + h * TD + d] = (_Float16)(of[nd][r] / linv[r]);
    }
  }
}

// ---------------------------------------------------------------------------
extern "C" void kernel_launch(void* const* d_in, const int* in_sizes, int n_in,
                              void* d_out, int out_size, void* d_ws, size_t ws_size,
                              hipStream_t stream) {
  const float* x    = (const float*)d_in[0];
  const float* wqkv = (const float*)d_in[1];
  const float* bqkv = (const float*)d_in[2];
  const float* wfin = (const float*)d_in[3];
  float* out = (float*)d_out;

  _Float16* xh  = (_Float16*)d_ws;          // [4096][768] row-major
  _Float16* wqh = xh + (size_t)TM * TK;     // fragment-native Wf
  _Float16* wfh = wqh + (size_t)NQKV * TK;  // fragment-native Wf
  _Float16* qb  = wfh + (size_t)TE * TE;    // [B,H,T,D] (pre-scaled)
  _Float16* kb  = qb + (size_t)TM * TE;     // K' fragment-native
  _Float16* vtb = kb + (size_t)TM * TE;     // V' fragment-native
  _Float16* ob  = vtb + (size_t)TM * TE;    // [4096][768] attn output

  cvt3<<<5376, 256, 0, stream>>>(x, wqkv, wfin, xh, wqh, wfh);
  gemm_nt<0, 64, NQKV / 128, 8><<<8 * 8 * (NQKV / 128), 256, 0, stream>>>(
      xh, wqh, bqkv, qb, kb, vtb, nullptr);
  attn_kernel<<<dim3(TT / 64 * TB * TH), 256, 0, stream>>>(qb, kb, vtb, ob);
  gemm_nt<1, 64, TE / 128, 8><<<8 * 8 * (TE / 128), 256, 0, stream>>>(
      ob, wfh, nullptr, nullptr, nullptr, nullptr, out);
}

// Round 18
// 81.752 us; speedup vs baseline: 1.0536x; 1.0488x over previous
//
#include <hip/hip_runtime.h>
#include <cstdint>

typedef _Float16 f16x8 __attribute__((ext_vector_type(8)));
typedef _Float16 f16x4 __attribute__((ext_vector_type(4)));
typedef float    f32x4 __attribute__((ext_vector_type(4)));

static constexpr int TB = 2;
static constexpr int TT = 2048;
static constexpr int TE = 768;
static constexpr int TH = 12;
static constexpr int TD = 64;
static constexpr int TM = TB * TT;      // 4096 rows (B*T)
static constexpr int TK = TE;           // 768 (K for both GEMMs)
static constexpr int NQKV = 3 * TE;     // 2304

#define SCALE_LOG2E 0.18033688011112042f  /* (1/sqrt(64)) * log2(e) */

// async global->LDS, 16B per lane. LDS dest is wave-uniform base + lane*16.
__device__ __forceinline__ void gload16(const void* g, void* lds) {
  __builtin_amdgcn_global_load_lds(
      (__attribute__((address_space(1))) void*)(uintptr_t)g,
      (__attribute__((address_space(3))) void*)(uint32_t)(uintptr_t)lds, 16, 0, 0);
}

// ---------------------------------------------------------------------------
// f32 -> f16 convert. x -> row-major f16. w_qkv / w_final -> FRAGMENT-NATIVE
// Wf layout: f16 idx(n,k) = ((n>>4)*24 + (k>>5))*512 + ((k>>3)&3)*128
//                           + (n&15)*8 + (k&7)
// ---------------------------------------------------------------------------
__global__ void cvt3(const float* __restrict__ x, const float* __restrict__ wq,
                     const float* __restrict__ wf, _Float16* __restrict__ xh,
                     _Float16* __restrict__ wqh, _Float16* __restrict__ wfh) {
  const int NX = TM * TK / 4, NW = NQKV * TK / 4;
  int i = blockIdx.x * 256 + threadIdx.x;
  if (i < NX) {
    float4 v = ((const float4*)x)[i];
    f16x4 o = {(_Float16)v.x, (_Float16)v.y, (_Float16)v.z, (_Float16)v.w};
    *(f16x4*)&xh[(size_t)i * 4] = o;
  } else {
    const float4* src; _Float16* dst; int j;
    if (i < NX + NW) { src = (const float4*)wq; dst = wqh; j = i - NX; }
    else             { src = (const float4*)wf; dst = wfh; j = i - NX - NW; }
    float4 v = src[j];
    f16x4 o = {(_Float16)v.x, (_Float16)v.y, (_Float16)v.z, (_Float16)v.w};
    const int flat = j * 4;
    const int n = flat / TK, k = flat % TK;
    const size_t idx = ((size_t)(n >> 4) * 24 + (k >> 5)) * 512 +
                       ((k >> 3) & 3) * 128 + (n & 15) * 8 + (k & 7);
    *(f16x4*)&dst[idx] = o;
  }
}

// ---------------------------------------------------------------------------
// NT GEMM (R15, race-fixed triple-buffer): C = A * Wf^T (+bias). 64x128
// tile, BK=64, 4 waves (64x32 out each). ONE barrier/K-step, prefetch
// distance 2: wait vmcnt -> barrier -> issue (ks+2) -> compute(ks).
// EPI=0: qkv epilogue (Q pre-scaled; K',V' fragment-native). EPI=1: f32 out.
// ---------------------------------------------------------------------------
template <int EPI, int MT, int NXT, int MPX>
__global__ __launch_bounds__(MT * 4)
void gemm_nt(const _Float16* __restrict__ A, const _Float16* __restrict__ Bw,
             const float* __restrict__ bias,
             _Float16* __restrict__ qb, _Float16* __restrict__ kb,
             _Float16* __restrict__ vtb, float* __restrict__ outp) {
  __shared__ _Float16 As[3][MT * 64];
  const int tid = threadIdx.x;
  const int w = tid >> 6, lane = tid & 63;
  const int lr = lane & 15, lk = lane >> 4;

  const int id = blockIdx.x;
  const int xcd = id & 7, j = id >> 3;
  const int m0 = (xcd * MPX + j / NXT) * MT;
  const int n0 = (j % NXT) * 128;
  const int wr = (MT == 128) ? (w >> 2) : 0;
  const int wc = (MT == 128) ? (w & 3) : w;

  f32x4 acc[4][2] = {};
  const char* Ab = (const char*)(A + (size_t)m0 * TK);
  const char* WB = (const char*)Bw;
  const int nb = (n0 >> 4) + wc * 2;
  constexpr int NS = TK / 64;  // 12 K-steps

  auto loadB = [&](int ks, f16x8 (&bf)[2][2]) {
#pragma unroll
    for (int ni = 0; ni < 2; ++ni)
#pragma unroll
      for (int kc = 0; kc < 2; ++kc)
        bf[ni][kc] = *(const f16x8*)(WB +
                                     ((size_t)(nb + ni) * 24 + ks * 2 + kc) * 1024 +
                                     lane * 16);
  };
  auto stageA = [&](int ks, _Float16* L) {
#pragma unroll
    for (int c = 0; c < 2; ++c) {
      int g = w * 2 + c;  // chunk of the MT*128B A tile
      int o = g * 1024 + lane * 16;
      int row = o >> 7, ch = (o >> 4) & 7;
      gload16(Ab + (size_t)row * (TK * 2) + ks * 128 + ((ch ^ (row & 7)) << 4),
              (char*)L + g * 1024);
    }
  };
  auto step = [&](f16x8 (&bc)[2][2], f16x8 (&bn)[2][2], _Float16* Lc,
                  _Float16* Ln, int ks) {
    if (ks < NS - 1) {
      asm volatile("s_waitcnt vmcnt(6)" ::: "memory");  // step ks's 6 landed
    } else {
      asm volatile("s_waitcnt vmcnt(0)" ::: "memory");
    }
    __builtin_amdgcn_s_barrier();  // publish ks; fence off compute(ks-1)
    if (ks < NS - 2) {
      loadB(ks + 2, bn);   // 4 reg loads (consumed at step ks+2)
      stageA(ks + 2, Ln);  // 2 gload16 -> As[(ks+2)%3] (WAR-safe)
    }
#pragma unroll
    for (int kc = 0; kc < 2; ++kc) {
      f16x8 af[4];
#pragma unroll
      for (int mi = 0; mi < 4; ++mi) {
        int row = wr * 64 + mi * 16 + lr;
        af[mi] = *(const f16x8*)&Lc[row * 64 + (((kc * 4 + lk) ^ (row & 7)) << 3)];
      }
#pragma unroll
      for (int mi = 0; mi < 4; ++mi)
#pragma unroll
        for (int ni = 0; ni < 2; ++ni)
          acc[mi][ni] = __builtin_amdgcn_mfma_f32_16x16x32_f16(af[mi], bc[ni][kc],
                                                               acc[mi][ni], 0, 0, 0);
    }
  };

  f16x8 b0[2][2], b1[2][2], b2[2][2];
  loadB(0, b0);
  stageA(0, As[0]);
  loadB(1, b1);
  stageA(1, As[1]);
  for (int kss = 0; kss < NS; kss += 3) {  // NS=12: buffer indices fold
    step(b0, b2, As[0], As[2], kss);
    step(b1, b0, As[1], As[0], kss + 1);
    step(b2, b1, As[2], As[1], kss + 2);
  }

  // epilogue: C layout col = lane&15 (N), row = (lane>>4)*4 + r
#pragma unroll
  for (int mi = 0; mi < 4; ++mi) {
#pragma unroll
    for (int ni = 0; ni < 2; ++ni) {
      const int col = n0 + wc * 32 + ni * 16 + lr;
#pragma unroll
      for (int r = 0; r < 4; ++r) {
        const int row = m0 + wr * 64 + mi * 16 + lk * 4 + r;
        float v = acc[mi][ni][r];
        if (EPI == 0) {
          v += bias[col];
          const int which = (col >= 2 * TE) ? 2 : (col >= TE ? 1 : 0);
          const int e = col - which * TE;
          const int h = e >> 6, d = e & 63;
          const int b = row >> 11, t = row & (TT - 1);
          const size_t hb = (size_t)(b * TH + h);
          if (which == 0) {
            qb[(hb * TT + t) * TD + d] = (_Float16)(v * SCALE_LOG2E);
          } else if (which == 1) {
            // K' fragment-native
            kb[((((hb * 128 + (t >> 4)) * 8 + (d >> 3)) * 16 + (t & 15)) * 8) +
               (d & 7)] = (_Float16)v;
          } else {
            // V' fragment-native
            const int kc = (t >> 5) & 1, hi = (t >> 4) & 1;
            const int lkv = (t >> 2) & 3, m = t & 3;
            vtb[((((((hb * 32 + (t >> 6)) * 4 + (d >> 4)) * 2 + kc) * 4 + lkv) *
                      16 +
                  (d & 15)) *
                 8) +
                (hi * 4 + m)] = (_Float16)v;
          }
        } else {
          outp[(size_t)row * TE + col] = v;
        }
      }
    }
  }
}

// ---------------------------------------------------------------------------
// Causal flash attention, BARRIER-FREE, NO LDS (R15 base) + DEFERRED
// CROSS-LANE REDUCTIONS: the per-phase softmax shfl chains are removed —
//  (1) lrun is kept LANE-PARTIAL (sum over this lane's 16 s-slots only;
//      associative, rescale multiplies the partial) and reduced ONCE in
//      the epilogue (2 shfl total instead of 2/phase);
//  (2) the max-agreement shfls run only INSIDE the rare defer-max rescale
//      branch — the wave-uniform decision comes from __any() (a vote, no
//      data movement). mrun stays wave-uniform (updated only under the
//      voted branch; first phase always triggers, establishing it).
// Grid 768 = 24 heads x 32 q-tiles (bh = id%24, qt = 31 - id/24). 4
// independent waves/block; wave w owns 16 q-rows. K,V fragment-native
// global -> contiguous 1KB wave loads to VGPR; kfA/kfB register dbuf, K
// prefetched 2 tiles ahead, V issued at phase start. SWAPPED QK^T
// (mfma(K,Q)): lane-local softmax; P never leaves registers.
// ---------------------------------------------------------------------------
__global__ __launch_bounds__(256)
void attn_kernel(const _Float16* __restrict__ qbuf, const _Float16* __restrict__ kbuf,
                 const _Float16* __restrict__ vtbuf, _Float16* __restrict__ ob) {
  const int tid = threadIdx.x, w = tid >> 6, lane = tid & 63;
  const int lr = lane & 15, lk = lane >> 4;

  const int id = blockIdx.x;        // 0..767
  const int bh = id % 24;
  const int qt = 31 - id / 24;      // heavy first, balanced per CU
  const int t0 = qt * 64;
  const int nt = qt + 1, ntm1 = qt;

  const _Float16* q = qbuf + (size_t)bh * (TT * TD);  // [T][64], pre-scaled
  const char* kbase =
      (const char*)(kbuf + (size_t)bh * (TT * TD)) + lk * 256 + lr * 16;
  const char* vbase =
      (const char*)(vtbuf + (size_t)bh * (TT * TD)) + lk * 256 + lr * 16;

  f16x8 qf[2];  // B-operand: Q[q=t0+w*16+lr][kc*32+lk*8 ..]
#pragma unroll
  for (int kc = 0; kc < 2; ++kc)
    qf[kc] = *(const f16x8*)&q[(size_t)(t0 + w * 16 + lr) * TD + kc * 32 + lk * 8];

  f32x4 of[4] = {};   // O[q=lk*4+r][d=nd*16+lr]
  float mrun = -1e30f;  // wave-uniform running max (log2 domain)
  float lrun = 0.f;     // LANE-PARTIAL denominator (this lane's 16 s-slots)

  f16x8 kfA[2][4], kfB[2][4], vf[2][4];

  // prologue: K(0) -> kfA, K(1) -> kfB (clamped)
#pragma unroll
  for (int kc = 0; kc < 2; ++kc)
#pragma unroll
    for (int ni = 0; ni < 4; ++ni)
      kfA[kc][ni] = *(const f16x8*)(kbase + ni * 2048 + kc * 1024);
  {
    const char* k1 = kbase + (size_t)(nt > 1 ? 1 : 0) * 8192;
#pragma unroll
    for (int kc = 0; kc < 2; ++kc)
#pragma unroll
      for (int ni = 0; ni < 4; ++ni)
        kfB[kc][ni] = *(const f16x8*)(k1 + ni * 2048 + kc * 1024);
  }

  auto phase = [&](f16x8 (&kf)[2][4], int st) {
    // issue V(st) loads (consumed by PV below; cover = QK^T + softmax)
    const char* vt = vbase + (size_t)st * 8192;
#pragma unroll
    for (int kc = 0; kc < 2; ++kc)
#pragma unroll
      for (int nd = 0; nd < 4; ++nd)
        vf[kc][nd] = *(const f16x8*)(vt + nd * 2048 + kc * 1024);

    // S^T: sa[ni] = mfma(K, Q): lane holds S[s=st*64+ni*16+lk*4+r][q=lr]
    f32x4 sa[4] = {};
    __builtin_amdgcn_s_setprio(1);
#pragma unroll
    for (int kc = 0; kc < 2; ++kc)
#pragma unroll
      for (int ni = 0; ni < 4; ++ni)
        sa[ni] =
            __builtin_amdgcn_mfma_f32_16x16x32_f16(kf[kc][ni], qf[kc], sa[ni], 0, 0, 0);
    __builtin_amdgcn_s_setprio(0);

    // prefetch K(st+2) into the buffer just consumed (clamped; 2-phase cover)
    {
      const int stp = (st + 2 <= ntm1) ? st + 2 : ntm1;
      const char* kt = kbase + (size_t)stp * 8192;
#pragma unroll
      for (int kc = 0; kc < 2; ++kc)
#pragma unroll
        for (int ni = 0; ni < 4; ++ni)
          kf[kc][ni] = *(const f16x8*)(kt + ni * 2048 + kc * 1024);
    }

    if (st == ntm1) {  // diagonal tile: causal mask (s > q)
      const int s0 = st * 64;
#pragma unroll
      for (int ni = 0; ni < 4; ++ni)
#pragma unroll
        for (int r = 0; r < 4; ++r)
          if (s0 + ni * 16 + lk * 4 + r > t0 + w * 16 + lr) sa[ni][r] = -1e30f;
    }

    // lane-local max over this lane's 16 values (NO cross-lane shfl here)
    float mx;
    {
      float m0_ = fmaxf(fmaxf(sa[0][0], sa[0][1]), fmaxf(sa[0][2], sa[0][3]));
      float m1_ = fmaxf(fmaxf(sa[1][0], sa[1][1]), fmaxf(sa[1][2], sa[1][3]));
      float m2_ = fmaxf(fmaxf(sa[2][0], sa[2][1]), fmaxf(sa[2][2], sa[2][3]));
      float m3_ = fmaxf(fmaxf(sa[3][0], sa[3][1]), fmaxf(sa[3][2], sa[3][3]));
      mx = fmaxf(fmaxf(m0_, m1_), fmaxf(m2_, m3_));
    }

    // defer-max: __any vote (no shfl); the agreement shfls run only in the
    // RARE rescale branch. mrun stays wave-uniform.
    if (__any(mx > mrun + 8.0f)) {
      mx = fmaxf(mx, __shfl_xor(mx, 16));
      mx = fmaxf(mx, __shfl_xor(mx, 32));
      mx = fmaxf(mx, __shfl_xor(mx, 1));
      mx = fmaxf(mx, __shfl_xor(mx, 2));
      mx = fmaxf(mx, __shfl_xor(mx, 4));
      mx = fmaxf(mx, __shfl_xor(mx, 8));  // full-wave max -> uniform
      float mn = fmaxf(mrun, mx);
      float al = __builtin_amdgcn_exp2f(mrun - mn);
      mrun = mn;
      lrun *= al;  // lane-partial scales identically
#pragma unroll
      for (int nd = 0; nd < 4; ++nd)
#pragma unroll
        for (int r = 0; r < 4; ++r) of[nd][r] *= al;  // al uniform -> no al4
    }

    // P = exp2(sa - mrun); pack PV A-fragments: pa[kc] slot 4*hi+m holds
    // P[q=lr][s = 32kc + 16hi + 4lk + m]  (hi = ni&1, m = r)
    f16x8 pa[2];
    {
      float rn[4];
#pragma unroll
      for (int ni = 0; ni < 4; ++ni) {
        float p0 = __builtin_amdgcn_exp2f(sa[ni][0] - mrun);
        float p1 = __builtin_amdgcn_exp2f(sa[ni][1] - mrun);
        float p2 = __builtin_amdgcn_exp2f(sa[ni][2] - mrun);
        float p3 = __builtin_amdgcn_exp2f(sa[ni][3] - mrun);
        rn[ni] = (p0 + p1) + (p2 + p3);
        pa[ni >> 1][(ni & 1) * 4 + 0] = (_Float16)p0;
        pa[ni >> 1][(ni & 1) * 4 + 1] = (_Float16)p1;
        pa[ni >> 1][(ni & 1) * 4 + 2] = (_Float16)p2;
        pa[ni >> 1][(ni & 1) * 4 + 3] = (_Float16)p3;
      }
      lrun += (rn[0] + rn[1]) + (rn[2] + rn[3]);  // lane-partial, NO shfl
    }

    // O += P V (B-fragment = vf, slot j = hi*4+m matches pa by construction)
    __builtin_amdgcn_s_setprio(1);
#pragma unroll
    for (int kc = 0; kc < 2; ++kc)
#pragma unroll
      for (int nd = 0; nd < 4; ++nd)
        of[nd] =
            __builtin_amdgcn_mfma_f32_16x16x32_f16(pa[kc], vf[kc][nd], of[nd], 0, 0, 0);
    __builtin_amdgcn_s_setprio(0);
  };

  int st = 0;
  while (st + 1 < nt) {
    phase(kfA, st);
    phase(kfB, st + 1);
    st += 2;
  }
  if (st < nt) phase(kfA, st);

  // epilogue: reduce the lane-partial lrun over the 4 replica lanes ONCE,
  // then fetch the row-owner's value (owner lane lr = q).
  lrun += __shfl_xor(lrun, 16);
  lrun += __shfl_xor(lrun, 32);
  float linv[4];
#pragma unroll
  for (int r = 0; r < 4; ++r) linv[r] = __shfl(lrun, lk * 4 + r);
  const int b = bh / TH, h = bh - b * TH;
#pragma unroll
  for (int nd = 0; nd < 4; ++nd) {
#pragma unroll
    for (int r = 0; r < 4; ++r) {
      int tg = t0 + w * 16 + lk * 4 + r;
      int d = nd * 16 + lr;
      ob[(size_t)(b * TT + tg) * TE + h * TD + d] = (_Float16)(of[nd][r] / linv[r]);
    }
  }
}

// ---------------------------------------------------------------------------
extern "C" void kernel_launch(void* const* d_in, const int* in_sizes, int n_in,
                              void* d_out, int out_size, void* d_ws, size_t ws_size,
                              hipStream_t stream) {
  const float* x    = (const float*)d_in[0];
  const float* wqkv = (const float*)d_in[1];
  const float* bqkv = (const float*)d_in[2];
  const float* wfin = (const float*)d_in[3];
  float* out = (float*)d_out;

  _Float16* xh  = (_Float16*)d_ws;          // [4096][768] row-major
  _Float16* wqh = xh + (size_t)TM * TK;     // fragment-native Wf
  _Float16* wfh = wqh + (size_t)NQKV * TK;  // fragment-native Wf
  _Float16* qb  = wfh + (size_t)TE * TE;    // [B,H,T,D] (pre-scaled)
  _Float16* kb  = qb + (size_t)TM * TE;     // K' fragment-native
  _Float16* vtb = kb + (size_t)TM * TE;     // V' fragment-native
  _Float16* ob  = vtb + (size_t)TM * TE;    // [4096][768] attn output

  cvt3<<<5376, 256, 0, stream>>>(x, wqkv, wfin, xh, wqh, wfh);
  gemm_nt<0, 64, NQKV / 128, 8><<<8 * 8 * (NQKV / 128), 256, 0, stream>>>(
      xh, wqh, bqkv, qb, kb, vtb, nullptr);
  attn_kernel<<<dim3(TT / 64 * TB * TH), 256, 0, stream>>>(qb, kb, vtb, ob);
  gemm_nt<1, 64, TE / 128, 8><<<8 * 8 * (TE / 128), 256, 0, stream>>>(
      ob, wfh, nullptr, nullptr, nullptr, nullptr, out);
}